// Round 9
// baseline (783.224 us; speedup 1.0000x reference)
//
#include <hip/hip_runtime.h>

#define T 2048
#define HID 4096
#define NH 32
#define NKV 8
#define HD 128
#define QKV_OUT ((NH + 2*NKV) * HD)   // 6144
#define SCALING 0.08838834764831843f  // 128^-0.5
#define ROPE_C 0.20762050593046014f   // log2(10000)/64

typedef __attribute__((ext_vector_type(8))) short bfrag;   // 8 bf16
typedef __attribute__((ext_vector_type(4))) float ffrag;   // 4 f32 acc
typedef __attribute__((ext_vector_type(4))) int  ifrag;    // 16 i8 / 4 i32 acc
typedef __attribute__((ext_vector_type(16))) char c16;

__device__ __forceinline__ short f2bf(float f) {
  unsigned u = __builtin_bit_cast(unsigned, f);
  u += 0x7fffu + ((u >> 16) & 1u);   // RNE
  return (short)(u >> 16);
}

// bf16x2 split: x ~= hi + lo, residual ~2^-17 * |x|
__device__ __forceinline__ void split2(float x, short& hi, short& lo) {
  unsigned u = __builtin_bit_cast(unsigned, x);
  unsigned uh = u + (0x7fffu + ((u >> 16) & 1u));
  hi = (short)(uh >> 16);
  float fh = __builtin_bit_cast(float, uh & 0xffff0000u);
  float r = x - fh;
  unsigned ur = __builtin_bit_cast(unsigned, r);
  ur += 0x7fffu + ((ur >> 16) & 1u);
  lo = (short)(ur >> 16);
}

// async global->LDS, 16 B per lane
__device__ __forceinline__ void gload_lds16(const void* g, void* l) {
  __builtin_amdgcn_global_load_lds(
      (const __attribute__((address_space(1))) unsigned int*)g,
      (__attribute__((address_space(3))) unsigned int*)l, 16, 0, 0);
}

// ---------------- fused a_sum + int8 pack of activations ----------------
__global__ __launch_bounds__(256)
void asum_conv(const int* __restrict__ qact, float* __restrict__ a_sum,
               char* __restrict__ a_i8) {
  __shared__ int red[256];
  const int t = blockIdx.x, tid = threadIdx.x;
  const int* row = qact + (size_t)t * HID + tid * 16;
  int s = 0;
  c16 o;
#pragma unroll
  for (int i = 0; i < 4; i++) {
    int4 v = *(const int4*)(row + i * 4);
    s += v.x + v.y + v.z + v.w;
    o[i*4+0] = (char)v.x; o[i*4+1] = (char)v.y;
    o[i*4+2] = (char)v.z; o[i*4+3] = (char)v.w;
  }
  *(c16*)(a_i8 + (size_t)t * HID + tid * 16) = o;
  red[tid] = s; __syncthreads();
  for (int off = 128; off > 0; off >>= 1) {
    if (tid < off) red[tid] += red[tid + off];
    __syncthreads();
  }
  if (tid == 0) a_sum[t] = (float)red[0];
}

// ---------------- int32 -> int8 pack (weights) ----------------
__global__ __launch_bounds__(256)
void conv_i2c(const int* __restrict__ src, char* __restrict__ dst, int n16) {
  int idx = blockIdx.x * 256 + threadIdx.x;
  if (idx >= n16) return;
  const int4* s4 = (const int4*)src + (size_t)idx * 4;
  c16 o;
#pragma unroll
  for (int j = 0; j < 4; j++) {
    int4 v = s4[j];
    o[j*4+0] = (char)v.x; o[j*4+1] = (char)v.y;
    o[j*4+2] = (char)v.z; o[j*4+3] = (char)v.w;
  }
  *(c16*)(dst + (size_t)idx * 16) = o;
}

// ---------------- W4A8 GEMM, exact i8 MFMA ----------------
template<bool WI8>
__global__ __launch_bounds__(256)
void gemm_i8(const char* __restrict__ A, const void* __restrict__ Wv,
             const float* __restrict__ s_a, const float* __restrict__ asum,
             const float* __restrict__ s_w, const float* __restrict__ z_w,
             float* __restrict__ C, int M, int N, int K) {
  __shared__ __align__(16) char As[128 * 64];
  __shared__ __align__(16) char Bs[128 * 64];
  const int tid = threadIdx.x;
  const int lane = tid & 63;
  const int quad = lane >> 4, l15 = lane & 15;
  const int wave = tid >> 6;
  const int wm = (wave >> 1) * 64, wn = (wave & 1) * 64;
  const int bm = blockIdx.y * 128, bn = blockIdx.x * 128;
  const int sr = tid >> 2, sc = (tid & 3) * 16;

  ifrag acc[4][4];
#pragma unroll
  for (int mi = 0; mi < 4; mi++)
#pragma unroll
    for (int ni = 0; ni < 4; ni++)
      acc[mi][ni] = (ifrag){0, 0, 0, 0};

  for (int k0 = 0; k0 < K; k0 += 64) {
#pragma unroll
    for (int it = 0; it < 2; it++)
      gload_lds16(A + (size_t)(bm + it * 64 + sr) * K + k0 + sc,
                  &As[it * 4096 + wave * 1024]);
    if constexpr (WI8) {
      const char* W = (const char*)Wv;
#pragma unroll
      for (int it = 0; it < 2; it++)
        gload_lds16(W + (size_t)(bn + it * 64 + sr) * K + k0 + sc,
                    &Bs[it * 4096 + wave * 1024]);
    } else {
      const int* W = (const int*)Wv;
      int r = tid >> 1, hh = (tid & 1) * 32;
#pragma unroll
      for (int i = 0; i < 2; i++) {
        c16 o;
#pragma unroll
        for (int j = 0; j < 4; j++) {
          int4 v = *(const int4*)(W + (size_t)(bn + r) * K + k0 + hh + i * 16 + j * 4);
          o[j*4+0] = (char)v.x; o[j*4+1] = (char)v.y;
          o[j*4+2] = (char)v.z; o[j*4+3] = (char)v.w;
        }
        *(c16*)&Bs[r * 64 + hh + i * 16] = o;
      }
    }
    __syncthreads();

    ifrag af[4], bfv[4];
#pragma unroll
    for (int mi = 0; mi < 4; mi++)
      af[mi] = *(const ifrag*)&As[(wm + mi * 16 + l15) * 64 + quad * 16];
#pragma unroll
    for (int ni = 0; ni < 4; ni++)
      bfv[ni] = *(const ifrag*)&Bs[(wn + ni * 16 + l15) * 64 + quad * 16];
#pragma unroll
    for (int mi = 0; mi < 4; mi++)
#pragma unroll
      for (int ni = 0; ni < 4; ni++)
        acc[mi][ni] = __builtin_amdgcn_mfma_i32_16x16x64_i8(
            af[mi], bfv[ni], acc[mi][ni], 0, 0, 0);
    __syncthreads();
  }

#pragma unroll
  for (int mi = 0; mi < 4; mi++) {
    int row0 = bm + wm + mi * 16 + quad * 4;
#pragma unroll
    for (int r = 0; r < 4; r++) {
      int row = row0 + r;
      float sa = s_a[row], av = asum[row];
#pragma unroll
      for (int ni = 0; ni < 4; ni++) {
        int col = bn + wn + ni * 16 + l15;
        C[(size_t)row * N + col] = (sa * s_w[col]) * ((float)acc[mi][ni][r] - z_w[col] * av);
      }
    }
  }
}

// ---------------- split K (rope fused) into bf16 hi/lo; V -> bf16 transposed
__global__ __launch_bounds__(256)
void split_kv(const float* __restrict__ qkv, const int* __restrict__ positions,
              short* __restrict__ Kh, short* __restrict__ Kl,
              short* __restrict__ Vth) {
  __shared__ __align__(16) short Vh_lds[128 * 72];
  const int kvh = blockIdx.y;
  const int t0 = blockIdx.x * 64;
  const int tid = threadIdx.x;
#pragma unroll
  for (int it = 0; it < 4; it++) {
    int c = tid + 256 * it;
    int key = c >> 4, dc = c & 15;
    const float* kr = qkv + (size_t)(t0 + key) * QKV_OUT
                      + (size_t)NH * HD + (size_t)kvh * HD;
    float4 a = *(const float4*)(kr + dc * 4);
    float4 b = *(const float4*)(kr + dc * 4 + 64);
    float av[4] = {a.x, a.y, a.z, a.w};
    float bv[4] = {b.x, b.y, b.z, b.w};
    float pos = (float)positions[t0 + key];
    short4 ha, la, hb, lb;
    short hh, ll;
#pragma unroll
    for (int jj = 0; jj < 4; jj++) {
      float fr = pos * exp2f(-ROPE_C * (float)(dc * 4 + jj));
      float sn, cs; sincosf(fr, &sn, &cs);
      float x1 = av[jj], x2 = bv[jj];
      float r1 = x1 * cs - x2 * sn;
      float r2 = x2 * cs + x1 * sn;
      split2(r1, hh, ll); ((short*)&ha)[jj] = hh; ((short*)&la)[jj] = ll;
      split2(r2, hh, ll); ((short*)&hb)[jj] = hh; ((short*)&lb)[jj] = ll;
    }
    size_t o1 = (size_t)kvh * T * HD + (size_t)(t0 + key) * HD + dc * 4;
    *(short4*)(Kh + o1) = ha;      *(short4*)(Kl + o1) = la;
    *(short4*)(Kh + o1 + 64) = hb; *(short4*)(Kl + o1 + 64) = lb;
  }
#pragma unroll
  for (int i = 0; i < 8; i++) {
    int c = tid + 256 * i;
    int key = c >> 5, dc = c & 31;
    float4 f = *(const float4*)(qkv + (size_t)(t0 + key) * QKV_OUT
                                + (size_t)(NH + NKV) * HD + (size_t)kvh * HD + dc * 4);
    Vh_lds[(dc*4+0)*72 + key] = f2bf(f.x);
    Vh_lds[(dc*4+1)*72 + key] = f2bf(f.y);
    Vh_lds[(dc*4+2)*72 + key] = f2bf(f.z);
    Vh_lds[(dc*4+3)*72 + key] = f2bf(f.w);
  }
  __syncthreads();
#pragma unroll
  for (int i = 0; i < 2; i++) {
    int c = tid + 256 * i;
    int row = c >> 2, cc = c & 3;
    size_t o = (size_t)kvh * HD * T + (size_t)row * T + t0 + cc * 8;
    *(bfrag*)(Vth + o) = *(const bfrag*)&Vh_lds[row * 72 + cc * 8];
  }
#pragma unroll
  for (int i = 0; i < 2; i++) {
    int c = tid + 256 * i;
    int row = c >> 2, cc = c & 3;
    size_t o = (size_t)kvh * HD * T + (size_t)row * T + t0 + 32 + cc * 8;
    *(bfrag*)(Vth + o) = *(const bfrag*)&Vh_lds[row * 72 + 32 + cc * 8];
  }
}

// ---------------- MFMA flash attention: 32 rows/wave, heavy-first ----------
// Block: (kvh, qtile of 32 rows), grid (64, NKV). Wave wv = head kvh*4+wv,
// two 16-row fragments sharing every K/V LDS fragment read (2x amortized).
// Q rope in-register (per-kc-pair to cap VGPRs). K hi/lo exact, V bf16.
// Next ktile K/V prefetched into registers during compute.
__global__ __launch_bounds__(256)
void attn_kernel(const float* __restrict__ qkv, const int* __restrict__ positions,
                 const short* __restrict__ Kh, const short* __restrict__ Kl,
                 const short* __restrict__ Vth,
                 float* __restrict__ attn) {
  __shared__ __align__(16) short Ksh[32 * 136];   // +4 banks/row: 2-way, free
  __shared__ __align__(16) short Ksl[32 * 136];
  __shared__ __align__(16) short Vsh[128 * 40];   // +20 banks/row: 2-way, free
  __shared__ __align__(16) short Psh[4 * 32 * 40];

  const int kvh = blockIdx.y;
  const int qt = gridDim.x - 1 - blockIdx.x;   // heavy first
  const int q0 = qt * 32;
  const int tid = threadIdx.x;
  const int lane = tid & 63;
  const int wv = tid >> 6;
  const int l15 = lane & 15, quad = lane >> 4;
  const int h = kvh * 4 + wv;
  short* Pw = Psh + wv * 32 * 40;
  const int nk = qt + 1;                       // 32-key ktiles 0..qt

  const short* KhB = Kh + (size_t)kvh * T * HD;
  const short* KlB = Kl + (size_t)kvh * T * HD;
  const short* VhB = Vth + (size_t)kvh * HD * T;

  const int kr = tid >> 4, kc8 = (tid & 15) * 8;   // K staging: rows kr, kr+16
  const int vd = tid >> 2, vc8 = (tid & 3) * 8;    // V staging: dims vd, vd+64

  bfrag rkh0, rkh1, rkl0, rkl1, rv0, rv1;
  auto preload = [&](int k0) {
    rkh0 = *(const bfrag*)(KhB + (size_t)(k0 + kr) * HD + kc8);
    rkh1 = *(const bfrag*)(KhB + (size_t)(k0 + kr + 16) * HD + kc8);
    rkl0 = *(const bfrag*)(KlB + (size_t)(k0 + kr) * HD + kc8);
    rkl1 = *(const bfrag*)(KlB + (size_t)(k0 + kr + 16) * HD + kc8);
    rv0  = *(const bfrag*)(VhB + (size_t)vd * T + k0 + vc8);
    rv1  = *(const bfrag*)(VhB + (size_t)(vd + 64) * T + k0 + vc8);
  };
  preload(0);

  // Q fragments (two 16-row sets), rope in-register per kc-pair, bf16x2 split
  bfrag qh[2][4], ql[2][4];
#pragma unroll
  for (int rs = 0; rs < 2; rs++) {
    const int trow = q0 + rs * 16 + l15;
    const float* qrow = qkv + (size_t)trow * QKV_OUT + (size_t)h * HD;
    const float pos = (float)positions[trow];
#pragma unroll
    for (int kc = 0; kc < 2; kc++) {           // pair (kc, kc+2)
      float4 a0 = *(const float4*)(qrow + kc * 32 + quad * 8);
      float4 a1 = *(const float4*)(qrow + kc * 32 + quad * 8 + 4);
      float4 b0 = *(const float4*)(qrow + (kc + 2) * 32 + quad * 8);
      float4 b1 = *(const float4*)(qrow + (kc + 2) * 32 + quad * 8 + 4);
      float xa[8] = {a0.x,a0.y,a0.z,a0.w,a1.x,a1.y,a1.z,a1.w};
      float xb[8] = {b0.x,b0.y,b0.z,b0.w,b1.x,b1.y,b1.z,b1.w};
#pragma unroll
      for (int j = 0; j < 8; j++) {
        int i = kc * 32 + quad * 8 + j;
        float fr = pos * exp2f(-ROPE_C * (float)i);
        float sn, cs; sincosf(fr, &sn, &cs);
        float x1 = xa[j], x2 = xb[j];
        float r1 = x1 * cs - x2 * sn;
        float r2 = x2 * cs + x1 * sn;
        short hi, lo;
        split2(r1, hi, lo); qh[rs][kc][j] = hi;     ql[rs][kc][j] = lo;
        split2(r2, hi, lo); qh[rs][kc + 2][j] = hi; ql[rs][kc + 2][j] = lo;
      }
    }
  }

  bfrag ones;
#pragma unroll
  for (int j = 0; j < 8; j++) ones[j] = (short)0x3f80;

  ffrag o[2][8], ol[2];
#pragma unroll
  for (int rs = 0; rs < 2; rs++) {
    ol[rs] = (ffrag){0.f, 0.f, 0.f, 0.f};
#pragma unroll
    for (int n = 0; n < 8; n++) o[rs][n] = (ffrag){0.f, 0.f, 0.f, 0.f};
  }
  float m_i[2][4] = {{-1e30f,-1e30f,-1e30f,-1e30f},{-1e30f,-1e30f,-1e30f,-1e30f}};

  for (int kt = 0; kt < nk; kt++) {
    const int k0 = kt << 5;
    __syncthreads();                         // prev LDS consumed
    *(bfrag*)&Ksh[kr * 136 + kc8] = rkh0;
    *(bfrag*)&Ksh[(kr + 16) * 136 + kc8] = rkh1;
    *(bfrag*)&Ksl[kr * 136 + kc8] = rkl0;
    *(bfrag*)&Ksl[(kr + 16) * 136 + kc8] = rkl1;
    *(bfrag*)&Vsh[vd * 40 + vc8] = rv0;
    *(bfrag*)&Vsh[(vd + 64) * 40 + vc8] = rv1;
    if (kt + 1 < nk) preload(k0 + 32);       // hidden behind compute
    __syncthreads();

    // ---- S = Q K^T; K fragments read once, used by both rowsets ----
    ffrag s[2][2];
    s[0][0] = (ffrag){0.f,0.f,0.f,0.f}; s[0][1] = (ffrag){0.f,0.f,0.f,0.f};
    s[1][0] = (ffrag){0.f,0.f,0.f,0.f}; s[1][1] = (ffrag){0.f,0.f,0.f,0.f};
#pragma unroll
    for (int n = 0; n < 2; n++) {
#pragma unroll
      for (int kc = 0; kc < 4; kc++) {
        bfrag bh = *(const bfrag*)&Ksh[(n*16 + l15) * 136 + kc*32 + quad*8];
        bfrag bl = *(const bfrag*)&Ksl[(n*16 + l15) * 136 + kc*32 + quad*8];
#pragma unroll
        for (int rs = 0; rs < 2; rs++) {
          s[rs][n] = __builtin_amdgcn_mfma_f32_16x16x32_bf16(qh[rs][kc], bh, s[rs][n], 0,0,0);
          s[rs][n] = __builtin_amdgcn_mfma_f32_16x16x32_bf16(qh[rs][kc], bl, s[rs][n], 0,0,0);
          s[rs][n] = __builtin_amdgcn_mfma_f32_16x16x32_bf16(ql[rs][kc], bh, s[rs][n], 0,0,0);
        }
      }
    }
    // ---- online softmax per rowset ----
    const bool last = (kt == nk - 1);
    bool anyup = false;
    float alpha[2][4];
#pragma unroll
    for (int rs = 0; rs < 2; rs++) {
      float sv[2][4];
#pragma unroll
      for (int n = 0; n < 2; n++)
#pragma unroll
        for (int r = 0; r < 4; r++) {
          float v = s[rs][n][r] * SCALING;
          if (last) {
            int key = k0 + n * 16 + l15;
            int row = q0 + rs * 16 + quad * 4 + r;
            if (key > row) v = -1e30f;
          }
          sv[n][r] = v;
        }
#pragma unroll
      for (int r = 0; r < 4; r++) {
        float mt = fmaxf(sv[0][r], sv[1][r]);
        mt = fmaxf(mt, __shfl_xor(mt, 1));
        mt = fmaxf(mt, __shfl_xor(mt, 2));
        mt = fmaxf(mt, __shfl_xor(mt, 4));
        mt = fmaxf(mt, __shfl_xor(mt, 8));
        float m_new = fmaxf(m_i[rs][r], mt);
        alpha[rs][r] = __expf(m_i[rs][r] - m_new);
        if (m_new > m_i[rs][r]) anyup = true;
        m_i[rs][r] = m_new;
      }
#pragma unroll
      for (int n = 0; n < 2; n++)
#pragma unroll
        for (int r = 0; r < 4; r++) {
          float p = __expf(sv[n][r] - m_i[rs][r]);
          Pw[(rs*16 + quad*4 + r) * 40 + n*16 + l15] = f2bf(p);
        }
    }
    if (__any(anyup)) {                      // wave-uniform skip when alpha==1
#pragma unroll
      for (int rs = 0; rs < 2; rs++) {
#pragma unroll
        for (int r = 0; r < 4; r++) ol[rs][r] *= alpha[rs][r];
#pragma unroll
        for (int n = 0; n < 8; n++)
#pragma unroll
          for (int r = 0; r < 4; r++) o[rs][n][r] *= alpha[rs][r];
      }
    }
    // ---- PV; V fragments read once, used by both rowsets ----
    bfrag ph0 = *(const bfrag*)&Pw[l15 * 40 + quad * 8];
    bfrag ph1 = *(const bfrag*)&Pw[(16 + l15) * 40 + quad * 8];
    ol[0] = __builtin_amdgcn_mfma_f32_16x16x32_bf16(ph0, ones, ol[0], 0,0,0);
    ol[1] = __builtin_amdgcn_mfma_f32_16x16x32_bf16(ph1, ones, ol[1], 0,0,0);
#pragma unroll
    for (int n = 0; n < 8; n++) {
      bfrag vh = *(const bfrag*)&Vsh[(n*16 + l15) * 40 + quad * 8];
      o[0][n] = __builtin_amdgcn_mfma_f32_16x16x32_bf16(ph0, vh, o[0][n], 0,0,0);
      o[1][n] = __builtin_amdgcn_mfma_f32_16x16x32_bf16(ph1, vh, o[1][n], 0,0,0);
    }
  }

#pragma unroll
  for (int rs = 0; rs < 2; rs++) {
    float inv[4];
#pragma unroll
    for (int r = 0; r < 4; r++) inv[r] = 1.f / ol[rs][r];
#pragma unroll
    for (int n = 0; n < 8; n++)
#pragma unroll
      for (int r = 0; r < 4; r++) {
        int row = q0 + rs * 16 + quad * 4 + r;
        attn[(size_t)row * HID + (size_t)h * HD + n * 16 + l15] = o[rs][n][r] * inv[r];
      }
  }
}

// ---------------- dynamic quant with sum (i8 out) ----------------
__global__ __launch_bounds__(256)
void quant_kernel(const float* __restrict__ x, char* __restrict__ q2,
                  float* __restrict__ s2, float* __restrict__ sum2) {
  __shared__ float red[256];
  const int t = blockIdx.x, tid = threadIdx.x;
  const float* row = x + (size_t)t * HID;
  float4 v[4];
  float m = 0.f;
#pragma unroll
  for (int i = 0; i < 4; i++) {
    v[i] = *(const float4*)(row + tid * 16 + i * 4);
    m = fmaxf(m, fmaxf(fmaxf(fabsf(v[i].x), fabsf(v[i].y)),
                       fmaxf(fabsf(v[i].z), fabsf(v[i].w))));
  }
  red[tid] = m; __syncthreads();
  for (int off = 128; off > 0; off >>= 1) {
    if (tid < off) red[tid] = fmaxf(red[tid], red[tid + off]);
    __syncthreads();
  }
  float s = fmaxf(red[0], 1e-8f) / 127.f;
  __syncthreads();
  float ssum = 0.f;
  c16 o;
#pragma unroll
  for (int i = 0; i < 4; i++) {
    float q;
    q = fminf(127.f, fmaxf(-127.f, rintf(v[i].x / s))); ssum += q; o[i*4+0] = (char)(int)q;
    q = fminf(127.f, fmaxf(-127.f, rintf(v[i].y / s))); ssum += q; o[i*4+1] = (char)(int)q;
    q = fminf(127.f, fmaxf(-127.f, rintf(v[i].z / s))); ssum += q; o[i*4+2] = (char)(int)q;
    q = fminf(127.f, fmaxf(-127.f, rintf(v[i].w / s))); ssum += q; o[i*4+3] = (char)(int)q;
  }
  *(c16*)(q2 + (size_t)t * HID + tid * 16) = o;
  red[tid] = ssum; __syncthreads();
  for (int off = 128; off > 0; off >>= 1) {
    if (tid < off) red[tid] += red[tid + off];
    __syncthreads();
  }
  if (tid == 0) { s2[t] = s; sum2[t] = red[0]; }
}

// ---------------- launch ----------------
extern "C" void kernel_launch(void* const* d_in, const int* in_sizes, int n_in,
                              void* d_out, int out_size, void* d_ws, size_t ws_size,
                              hipStream_t stream) {
  const int*   positions   = (const int*)d_in[0];
  const int*   q_act       = (const int*)d_in[1];
  const float* act_scale   = (const float*)d_in[2];
  const int*   w_qkv_q     = (const int*)d_in[3];
  const float* w_qkv_scale = (const float*)d_in[4];
  const float* w_qkv_zero  = (const float*)d_in[5];
  const int*   w_o_q       = (const int*)d_in[6];
  const float* w_o_scale   = (const float*)d_in[7];
  const float* w_o_zero    = (const float*)d_in[8];
  float* out = (float*)d_out;

  size_t off = 0;
  auto alloc = [&](size_t bytes) -> void* {
    void* p = (char*)d_ws + off;
    off += (bytes + 255) & ~(size_t)255;
    return p;
  };
  float* qkv   = (float*)alloc((size_t)T * QKV_OUT * 4);
  char*  a_i8  = (char*)alloc((size_t)T * HID);
  char*  q2    = (char*)alloc((size_t)T * HID);
  short* Kh    = (short*)alloc((size_t)NKV * T * HD * 2);
  short* Kl    = (short*)alloc((size_t)NKV * T * HD * 2);
  short* Vth   = (short*)alloc((size_t)NKV * T * HD * 2);
  float* a_sum = (float*)alloc(T * 4);
  float* s2    = (float*)alloc(T * 4);
  float* sum2  = (float*)alloc(T * 4);
  char* wqkv_i8 = (char*)alloc((size_t)QKV_OUT * HID);
  char* wo_i8   = (char*)alloc((size_t)HID * HID);
  const bool wconv = (ws_size >= off);   // constant across calls

  asum_conv<<<T, 256, 0, stream>>>(q_act, a_sum, a_i8);
  if (wconv) {
    conv_i2c<<<(QKV_OUT * HID / 16 + 255) / 256, 256, 0, stream>>>(w_qkv_q, wqkv_i8, QKV_OUT * HID / 16);
    conv_i2c<<<(HID * HID / 16 + 255) / 256, 256, 0, stream>>>(w_o_q, wo_i8, HID * HID / 16);
    gemm_i8<true><<<dim3(QKV_OUT / 128, T / 128), 256, 0, stream>>>(
        a_i8, wqkv_i8, act_scale, a_sum, w_qkv_scale, w_qkv_zero, qkv, T, QKV_OUT, HID);
  } else {
    gemm_i8<false><<<dim3(QKV_OUT / 128, T / 128), 256, 0, stream>>>(
        a_i8, w_qkv_q, act_scale, a_sum, w_qkv_scale, w_qkv_zero, qkv, T, QKV_OUT, HID);
  }
  split_kv<<<dim3(T / 64, NKV), 256, 0, stream>>>(qkv, positions, Kh, Kl, Vth);
  attn_kernel<<<dim3(64, NKV), 256, 0, stream>>>(qkv, positions, Kh, Kl, Vth, out);
  quant_kernel<<<T, 256, 0, stream>>>(out, q2, s2, sum2);
  if (wconv) {
    gemm_i8<true><<<dim3(HID / 128, T / 128), 256, 0, stream>>>(
        q2, wo_i8, s2, sum2, w_o_scale, w_o_zero, out, T, HID, HID);
  } else {
    gemm_i8<false><<<dim3(HID / 128, T / 128), 256, 0, stream>>>(
        q2, w_o_q, s2, sum2, w_o_scale, w_o_zero, out, T, HID, HID);
  }
}

// Round 10
// 546.662 us; speedup vs baseline: 1.4327x; 1.4327x over previous
//
#include <hip/hip_runtime.h>

#define T 2048
#define HID 4096
#define NH 32
#define NKV 8
#define HD 128
#define QKV_OUT ((NH + 2*NKV) * HD)   // 6144
#define SCALING 0.08838834764831843f  // 128^-0.5
#define ROPE_C 0.20762050593046014f   // log2(10000)/64

typedef __attribute__((ext_vector_type(8))) short bfrag;   // 8 bf16
typedef __attribute__((ext_vector_type(4))) float ffrag;   // 4 f32 acc
typedef __attribute__((ext_vector_type(4))) int  ifrag;    // 16 i8 / 4 i32 acc
typedef __attribute__((ext_vector_type(16))) char c16;

__device__ __forceinline__ short f2bf(float f) {
  unsigned u = __builtin_bit_cast(unsigned, f);
  u += 0x7fffu + ((u >> 16) & 1u);   // RNE
  return (short)(u >> 16);
}

// bf16x2 split: x ~= hi + lo, residual ~2^-17 * |x|
__device__ __forceinline__ void split2(float x, short& hi, short& lo) {
  unsigned u = __builtin_bit_cast(unsigned, x);
  unsigned uh = u + (0x7fffu + ((u >> 16) & 1u));
  hi = (short)(uh >> 16);
  float fh = __builtin_bit_cast(float, uh & 0xffff0000u);
  float r = x - fh;
  unsigned ur = __builtin_bit_cast(unsigned, r);
  ur += 0x7fffu + ((ur >> 16) & 1u);
  lo = (short)(ur >> 16);
}

// async global->LDS, 16 B per lane
__device__ __forceinline__ void gload_lds16(const void* g, void* l) {
  __builtin_amdgcn_global_load_lds(
      (const __attribute__((address_space(1))) unsigned int*)g,
      (__attribute__((address_space(3))) unsigned int*)l, 16, 0, 0);
}

// ---------------- fused a_sum + int8 pack of activations ----------------
__global__ __launch_bounds__(256)
void asum_conv(const int* __restrict__ qact, float* __restrict__ a_sum,
               char* __restrict__ a_i8) {
  __shared__ int red[256];
  const int t = blockIdx.x, tid = threadIdx.x;
  const int* row = qact + (size_t)t * HID + tid * 16;
  int s = 0;
  c16 o;
#pragma unroll
  for (int i = 0; i < 4; i++) {
    int4 v = *(const int4*)(row + i * 4);
    s += v.x + v.y + v.z + v.w;
    o[i*4+0] = (char)v.x; o[i*4+1] = (char)v.y;
    o[i*4+2] = (char)v.z; o[i*4+3] = (char)v.w;
  }
  *(c16*)(a_i8 + (size_t)t * HID + tid * 16) = o;
  red[tid] = s; __syncthreads();
  for (int off = 128; off > 0; off >>= 1) {
    if (tid < off) red[tid] += red[tid + off];
    __syncthreads();
  }
  if (tid == 0) a_sum[t] = (float)red[0];
}

// ---------------- int32 -> int8 pack (weights) ----------------
__global__ __launch_bounds__(256)
void conv_i2c(const int* __restrict__ src, char* __restrict__ dst, int n16) {
  int idx = blockIdx.x * 256 + threadIdx.x;
  if (idx >= n16) return;
  const int4* s4 = (const int4*)src + (size_t)idx * 4;
  c16 o;
#pragma unroll
  for (int j = 0; j < 4; j++) {
    int4 v = s4[j];
    o[j*4+0] = (char)v.x; o[j*4+1] = (char)v.y;
    o[j*4+2] = (char)v.z; o[j*4+3] = (char)v.w;
  }
  *(c16*)(dst + (size_t)idx * 16) = o;
}

// ---------------- W4A8 GEMM, exact i8 MFMA ----------------
template<bool WI8>
__global__ __launch_bounds__(256)
void gemm_i8(const char* __restrict__ A, const void* __restrict__ Wv,
             const float* __restrict__ s_a, const float* __restrict__ asum,
             const float* __restrict__ s_w, const float* __restrict__ z_w,
             float* __restrict__ C, int M, int N, int K) {
  __shared__ __align__(16) char As[128 * 64];
  __shared__ __align__(16) char Bs[128 * 64];
  const int tid = threadIdx.x;
  const int lane = tid & 63;
  const int quad = lane >> 4, l15 = lane & 15;
  const int wave = tid >> 6;
  const int wm = (wave >> 1) * 64, wn = (wave & 1) * 64;
  const int bm = blockIdx.y * 128, bn = blockIdx.x * 128;
  const int sr = tid >> 2, sc = (tid & 3) * 16;

  ifrag acc[4][4];
#pragma unroll
  for (int mi = 0; mi < 4; mi++)
#pragma unroll
    for (int ni = 0; ni < 4; ni++)
      acc[mi][ni] = (ifrag){0, 0, 0, 0};

  for (int k0 = 0; k0 < K; k0 += 64) {
#pragma unroll
    for (int it = 0; it < 2; it++)
      gload_lds16(A + (size_t)(bm + it * 64 + sr) * K + k0 + sc,
                  &As[it * 4096 + wave * 1024]);
    if constexpr (WI8) {
      const char* W = (const char*)Wv;
#pragma unroll
      for (int it = 0; it < 2; it++)
        gload_lds16(W + (size_t)(bn + it * 64 + sr) * K + k0 + sc,
                    &Bs[it * 4096 + wave * 1024]);
    } else {
      const int* W = (const int*)Wv;
      int r = tid >> 1, hh = (tid & 1) * 32;
#pragma unroll
      for (int i = 0; i < 2; i++) {
        c16 o;
#pragma unroll
        for (int j = 0; j < 4; j++) {
          int4 v = *(const int4*)(W + (size_t)(bn + r) * K + k0 + hh + i * 16 + j * 4);
          o[j*4+0] = (char)v.x; o[j*4+1] = (char)v.y;
          o[j*4+2] = (char)v.z; o[j*4+3] = (char)v.w;
        }
        *(c16*)&Bs[r * 64 + hh + i * 16] = o;
      }
    }
    __syncthreads();

    ifrag af[4], bfv[4];
#pragma unroll
    for (int mi = 0; mi < 4; mi++)
      af[mi] = *(const ifrag*)&As[(wm + mi * 16 + l15) * 64 + quad * 16];
#pragma unroll
    for (int ni = 0; ni < 4; ni++)
      bfv[ni] = *(const ifrag*)&Bs[(wn + ni * 16 + l15) * 64 + quad * 16];
#pragma unroll
    for (int mi = 0; mi < 4; mi++)
#pragma unroll
      for (int ni = 0; ni < 4; ni++)
        acc[mi][ni] = __builtin_amdgcn_mfma_i32_16x16x64_i8(
            af[mi], bfv[ni], acc[mi][ni], 0, 0, 0);
    __syncthreads();
  }

#pragma unroll
  for (int mi = 0; mi < 4; mi++) {
    int row0 = bm + wm + mi * 16 + quad * 4;
#pragma unroll
    for (int r = 0; r < 4; r++) {
      int row = row0 + r;
      float sa = s_a[row], av = asum[row];
#pragma unroll
      for (int ni = 0; ni < 4; ni++) {
        int col = bn + wn + ni * 16 + l15;
        C[(size_t)row * N + col] = (sa * s_w[col]) * ((float)acc[mi][ni][r] - z_w[col] * av);
      }
    }
  }
}

// ---- split/rope: y<NKV: K rope->hi/lo + V->bf16 transposed; else Q rope in-place
__global__ __launch_bounds__(256)
void split_kv(float* __restrict__ qkv, const int* __restrict__ positions,
              short* __restrict__ Kh, short* __restrict__ Kl,
              short* __restrict__ Vth) {
  __shared__ __align__(16) short Vh_lds[128 * 72];
  const int y = blockIdx.y;
  const int t0 = blockIdx.x * 64;
  const int tid = threadIdx.x;

  if (y >= NKV) {                      // ---- Q: rope in place ----
    const int h = y - NKV;
#pragma unroll
    for (int it = 0; it < 4; it++) {
      int c = tid + 256 * it;
      int key = c >> 4, dc = c & 15;
      float* qr = qkv + (size_t)(t0 + key) * QKV_OUT + (size_t)h * HD;
      float4 a = *(const float4*)(qr + dc * 4);
      float4 b = *(const float4*)(qr + dc * 4 + 64);
      float av[4] = {a.x, a.y, a.z, a.w};
      float bv[4] = {b.x, b.y, b.z, b.w};
      float pos = (float)positions[t0 + key];
#pragma unroll
      for (int jj = 0; jj < 4; jj++) {
        float fr = pos * exp2f(-ROPE_C * (float)(dc * 4 + jj));
        float sn, cs; sincosf(fr, &sn, &cs);
        float x1 = av[jj], x2 = bv[jj];
        av[jj] = x1 * cs - x2 * sn;
        bv[jj] = x2 * cs + x1 * sn;
      }
      *(float4*)(qr + dc * 4)      = make_float4(av[0], av[1], av[2], av[3]);
      *(float4*)(qr + dc * 4 + 64) = make_float4(bv[0], bv[1], bv[2], bv[3]);
    }
    return;
  }

  const int kvh = y;
  // K: rope + hi/lo split
#pragma unroll
  for (int it = 0; it < 4; it++) {
    int c = tid + 256 * it;
    int key = c >> 4, dc = c & 15;
    const float* kr = qkv + (size_t)(t0 + key) * QKV_OUT
                      + (size_t)NH * HD + (size_t)kvh * HD;
    float4 a = *(const float4*)(kr + dc * 4);
    float4 b = *(const float4*)(kr + dc * 4 + 64);
    float av[4] = {a.x, a.y, a.z, a.w};
    float bv[4] = {b.x, b.y, b.z, b.w};
    float pos = (float)positions[t0 + key];
    short4 ha, la, hb, lb;
    short hh, ll;
#pragma unroll
    for (int jj = 0; jj < 4; jj++) {
      float fr = pos * exp2f(-ROPE_C * (float)(dc * 4 + jj));
      float sn, cs; sincosf(fr, &sn, &cs);
      float x1 = av[jj], x2 = bv[jj];
      float r1 = x1 * cs - x2 * sn;
      float r2 = x2 * cs + x1 * sn;
      split2(r1, hh, ll); ((short*)&ha)[jj] = hh; ((short*)&la)[jj] = ll;
      split2(r2, hh, ll); ((short*)&hb)[jj] = hh; ((short*)&lb)[jj] = ll;
    }
    size_t o1 = (size_t)kvh * T * HD + (size_t)(t0 + key) * HD + dc * 4;
    *(short4*)(Kh + o1) = ha;      *(short4*)(Kl + o1) = la;
    *(short4*)(Kh + o1 + 64) = hb; *(short4*)(Kl + o1 + 64) = lb;
  }
  // V -> bf16 transposed
#pragma unroll
  for (int i = 0; i < 8; i++) {
    int c = tid + 256 * i;
    int key = c >> 5, dc = c & 31;
    float4 f = *(const float4*)(qkv + (size_t)(t0 + key) * QKV_OUT
                                + (size_t)(NH + NKV) * HD + (size_t)kvh * HD + dc * 4);
    Vh_lds[(dc*4+0)*72 + key] = f2bf(f.x);
    Vh_lds[(dc*4+1)*72 + key] = f2bf(f.y);
    Vh_lds[(dc*4+2)*72 + key] = f2bf(f.z);
    Vh_lds[(dc*4+3)*72 + key] = f2bf(f.w);
  }
  __syncthreads();
#pragma unroll
  for (int i = 0; i < 2; i++) {
    int c = tid + 256 * i;
    int row = c >> 2, cc = c & 3;
    size_t o = (size_t)kvh * HD * T + (size_t)row * T + t0 + cc * 8;
    *(bfrag*)(Vth + o) = *(const bfrag*)&Vh_lds[row * 72 + cc * 8];
  }
#pragma unroll
  for (int i = 0; i < 2; i++) {
    int c = tid + 256 * i;
    int row = c >> 2, cc = c & 3;
    size_t o = (size_t)kvh * HD * T + (size_t)row * T + t0 + 32 + cc * 8;
    *(bfrag*)(Vth + o) = *(const bfrag*)&Vh_lds[row * 72 + 32 + cc * 8];
  }
}

// ---------------- MFMA flash attention, balanced pairs + reg prefetch ------
// (R7 structure: best measured.) Block: (kvh, pair). Two passes: qtile
// 127-pair (heavy) then pair (light); 65 ktiles/block, uniform. Wave wv =
// q-head kvh*4+wv, 16 rows. K hi/lo exact, V bf16, P bf16, l via ones-MFMA.
// Next ktile K/V prefetched into registers. anyup skips O-rescale.
__global__ __launch_bounds__(256)
void attn_kernel(const float* __restrict__ qkv,
                 const short* __restrict__ Kh, const short* __restrict__ Kl,
                 const short* __restrict__ Vth,
                 float* __restrict__ attn) {
  __shared__ __align__(16) short Ksh[32 * 136];   // +4 banks/row: 2-way, free
  __shared__ __align__(16) short Ksl[32 * 136];
  __shared__ __align__(16) short Vsh[128 * 40];   // +20 banks/row: 2-way, free
  __shared__ __align__(16) short Psh[4 * 16 * 40];

  const int kvh = blockIdx.y;
  const int pair = blockIdx.x;                 // 0..63
  const int tid = threadIdx.x;
  const int lane = tid & 63;
  const int wv = tid >> 6;
  const int l15 = lane & 15, quad = lane >> 4;
  const int h = kvh * 4 + wv;
  short* Pw = Psh + wv * 16 * 40;

  const short* KhB = Kh + (size_t)kvh * T * HD;
  const short* KlB = Kl + (size_t)kvh * T * HD;
  const short* VhB = Vth + (size_t)kvh * HD * T;

  const int kr = tid >> 4, kc8 = (tid & 15) * 8;   // K staging: rows kr, kr+16
  const int vd = tid >> 2, vc8 = (tid & 3) * 8;    // V staging: dims vd, vd+64

  bfrag rkh0, rkh1, rkl0, rkl1, rv0, rv1;
  auto preload = [&](int k0) {
    rkh0 = *(const bfrag*)(KhB + (size_t)(k0 + kr) * HD + kc8);
    rkh1 = *(const bfrag*)(KhB + (size_t)(k0 + kr + 16) * HD + kc8);
    rkl0 = *(const bfrag*)(KlB + (size_t)(k0 + kr) * HD + kc8);
    rkl1 = *(const bfrag*)(KlB + (size_t)(k0 + kr + 16) * HD + kc8);
    rv0  = *(const bfrag*)(VhB + (size_t)vd * T + k0 + vc8);
    rv1  = *(const bfrag*)(VhB + (size_t)(vd + 64) * T + k0 + vc8);
  };
  preload(0);

  bfrag ones;
#pragma unroll
  for (int j = 0; j < 8; j++) ones[j] = (short)0x3f80;

  for (int pass = 0; pass < 2; pass++) {
    const int qt = pass ? pair : 127 - pair;
    const int q0 = qt * 16;
    const int nk = (q0 >> 5) + 1;              // keys 0..q0+15

    // Q fragments (already roped fp32), bf16x2 split
    bfrag qh[4], ql[4];
    const float* qrow = qkv + (size_t)(q0 + l15) * QKV_OUT + (size_t)h * HD;
#pragma unroll
    for (int kc = 0; kc < 4; kc++) {
      float4 f0 = *(const float4*)(qrow + kc * 32 + quad * 8);
      float4 f1 = *(const float4*)(qrow + kc * 32 + quad * 8 + 4);
      float fv[8] = {f0.x, f0.y, f0.z, f0.w, f1.x, f1.y, f1.z, f1.w};
#pragma unroll
      for (int j = 0; j < 8; j++) {
        short hi, lo; split2(fv[j], hi, lo);
        qh[kc][j] = hi; ql[kc][j] = lo;
      }
    }

    ffrag o[8], ol;
    ol = (ffrag){0.f, 0.f, 0.f, 0.f};
#pragma unroll
    for (int n = 0; n < 8; n++) o[n] = (ffrag){0.f, 0.f, 0.f, 0.f};
    float m_i[4] = {-1e30f, -1e30f, -1e30f, -1e30f};

    for (int kt = 0; kt < nk; kt++) {
      const int k0 = kt << 5;
      __syncthreads();                         // prev LDS consumed
      *(bfrag*)&Ksh[kr * 136 + kc8] = rkh0;
      *(bfrag*)&Ksh[(kr + 16) * 136 + kc8] = rkh1;
      *(bfrag*)&Ksl[kr * 136 + kc8] = rkl0;
      *(bfrag*)&Ksl[(kr + 16) * 136 + kc8] = rkl1;
      *(bfrag*)&Vsh[vd * 40 + vc8] = rv0;
      *(bfrag*)&Vsh[(vd + 64) * 40 + vc8] = rv1;
      if (kt + 1 < nk) preload(k0 + 32);       // hidden behind compute
      else if (pass == 0) preload(0);          // prime next pass
      __syncthreads();

      // ---- S = Q K^T (exact via hi/lo split) ----
      ffrag s[2];
      s[0] = (ffrag){0.f,0.f,0.f,0.f}; s[1] = (ffrag){0.f,0.f,0.f,0.f};
#pragma unroll
      for (int n = 0; n < 2; n++) {
#pragma unroll
        for (int kc = 0; kc < 4; kc++) {
          bfrag bh = *(const bfrag*)&Ksh[(n*16 + l15) * 136 + kc*32 + quad*8];
          bfrag bl = *(const bfrag*)&Ksl[(n*16 + l15) * 136 + kc*32 + quad*8];
          s[n] = __builtin_amdgcn_mfma_f32_16x16x32_bf16(qh[kc], bh, s[n], 0,0,0);
          s[n] = __builtin_amdgcn_mfma_f32_16x16x32_bf16(qh[kc], bl, s[n], 0,0,0);
          s[n] = __builtin_amdgcn_mfma_f32_16x16x32_bf16(ql[kc], bh, s[n], 0,0,0);
        }
      }
      // ---- online softmax ----
      const bool last = (kt == nk - 1);
      float sv[2][4];
#pragma unroll
      for (int n = 0; n < 2; n++)
#pragma unroll
        for (int r = 0; r < 4; r++) {
          float v = s[n][r] * SCALING;
          if (last) {
            int key = k0 + n * 16 + l15;
            int row = q0 + quad * 4 + r;
            if (key > row) v = -1e30f;
          }
          sv[n][r] = v;
        }
      float alpha[4];
      bool anyup = false;
#pragma unroll
      for (int r = 0; r < 4; r++) {
        float mt = fmaxf(sv[0][r], sv[1][r]);
        mt = fmaxf(mt, __shfl_xor(mt, 1));
        mt = fmaxf(mt, __shfl_xor(mt, 2));
        mt = fmaxf(mt, __shfl_xor(mt, 4));
        mt = fmaxf(mt, __shfl_xor(mt, 8));
        float m_new = fmaxf(m_i[r], mt);
        alpha[r] = __expf(m_i[r] - m_new);
        if (m_new > m_i[r]) anyup = true;
        m_i[r] = m_new;
      }
#pragma unroll
      for (int n = 0; n < 2; n++)
#pragma unroll
        for (int r = 0; r < 4; r++) {
          float p = __expf(sv[n][r] - m_i[r]);
          Pw[(quad*4 + r) * 40 + n*16 + l15] = f2bf(p);
        }
      if (__any(anyup)) {                      // wave-uniform rescale skip
#pragma unroll
        for (int r = 0; r < 4; r++) ol[r] *= alpha[r];
#pragma unroll
        for (int n = 0; n < 8; n++)
#pragma unroll
          for (int r = 0; r < 4; r++) o[n][r] *= alpha[r];
      }
      // ---- PV; l via ones-MFMA (same wave wrote Pw, no barrier) ----
      bfrag ph = *(const bfrag*)&Pw[l15 * 40 + quad * 8];
      ol = __builtin_amdgcn_mfma_f32_16x16x32_bf16(ph, ones, ol, 0,0,0);
#pragma unroll
      for (int n = 0; n < 8; n++) {
        bfrag vh = *(const bfrag*)&Vsh[(n*16 + l15) * 40 + quad * 8];
        o[n] = __builtin_amdgcn_mfma_f32_16x16x32_bf16(ph, vh, o[n], 0,0,0);
      }
    }

    float inv[4];
#pragma unroll
    for (int r = 0; r < 4; r++) inv[r] = 1.f / ol[r];
#pragma unroll
    for (int n = 0; n < 8; n++)
#pragma unroll
      for (int r = 0; r < 4; r++) {
        int row = q0 + quad * 4 + r;
        attn[(size_t)row * HID + (size_t)h * HD + n * 16 + l15] = o[n][r] * inv[r];
      }
  }
}

// ---------------- dynamic quant with sum (i8 out) ----------------
__global__ __launch_bounds__(256)
void quant_kernel(const float* __restrict__ x, char* __restrict__ q2,
                  float* __restrict__ s2, float* __restrict__ sum2) {
  __shared__ float red[256];
  const int t = blockIdx.x, tid = threadIdx.x;
  const float* row = x + (size_t)t * HID;
  float4 v[4];
  float m = 0.f;
#pragma unroll
  for (int i = 0; i < 4; i++) {
    v[i] = *(const float4*)(row + tid * 16 + i * 4);
    m = fmaxf(m, fmaxf(fmaxf(fabsf(v[i].x), fabsf(v[i].y)),
                       fmaxf(fabsf(v[i].z), fabsf(v[i].w))));
  }
  red[tid] = m; __syncthreads();
  for (int off = 128; off > 0; off >>= 1) {
    if (tid < off) red[tid] = fmaxf(red[tid], red[tid + off]);
    __syncthreads();
  }
  float s = fmaxf(red[0], 1e-8f) / 127.f;
  __syncthreads();
  float ssum = 0.f;
  c16 o;
#pragma unroll
  for (int i = 0; i < 4; i++) {
    float q;
    q = fminf(127.f, fmaxf(-127.f, rintf(v[i].x / s))); ssum += q; o[i*4+0] = (char)(int)q;
    q = fminf(127.f, fmaxf(-127.f, rintf(v[i].y / s))); ssum += q; o[i*4+1] = (char)(int)q;
    q = fminf(127.f, fmaxf(-127.f, rintf(v[i].z / s))); ssum += q; o[i*4+2] = (char)(int)q;
    q = fminf(127.f, fmaxf(-127.f, rintf(v[i].w / s))); ssum += q; o[i*4+3] = (char)(int)q;
  }
  *(c16*)(q2 + (size_t)t * HID + tid * 16) = o;
  red[tid] = ssum; __syncthreads();
  for (int off = 128; off > 0; off >>= 1) {
    if (tid < off) red[tid] += red[tid + off];
    __syncthreads();
  }
  if (tid == 0) { s2[t] = s; sum2[t] = red[0]; }
}

// ---------------- launch ----------------
extern "C" void kernel_launch(void* const* d_in, const int* in_sizes, int n_in,
                              void* d_out, int out_size, void* d_ws, size_t ws_size,
                              hipStream_t stream) {
  const int*   positions   = (const int*)d_in[0];
  const int*   q_act       = (const int*)d_in[1];
  const float* act_scale   = (const float*)d_in[2];
  const int*   w_qkv_q     = (const int*)d_in[3];
  const float* w_qkv_scale = (const float*)d_in[4];
  const float* w_qkv_zero  = (const float*)d_in[5];
  const int*   w_o_q       = (const int*)d_in[6];
  const float* w_o_scale   = (const float*)d_in[7];
  const float* w_o_zero    = (const float*)d_in[8];
  float* out = (float*)d_out;

  size_t off = 0;
  auto alloc = [&](size_t bytes) -> void* {
    void* p = (char*)d_ws + off;
    off += (bytes + 255) & ~(size_t)255;
    return p;
  };
  float* qkv   = (float*)alloc((size_t)T * QKV_OUT * 4);
  char*  a_i8  = (char*)alloc((size_t)T * HID);
  char*  q2    = (char*)alloc((size_t)T * HID);
  short* Kh    = (short*)alloc((size_t)NKV * T * HD * 2);
  short* Kl    = (short*)alloc((size_t)NKV * T * HD * 2);
  short* Vth   = (short*)alloc((size_t)NKV * T * HD * 2);
  float* a_sum = (float*)alloc(T * 4);
  float* s2    = (float*)alloc(T * 4);
  float* sum2  = (float*)alloc(T * 4);
  char* wqkv_i8 = (char*)alloc((size_t)QKV_OUT * HID);
  char* wo_i8   = (char*)alloc((size_t)HID * HID);
  const bool wconv = (ws_size >= off);   // constant across calls

  asum_conv<<<T, 256, 0, stream>>>(q_act, a_sum, a_i8);
  if (wconv) {
    conv_i2c<<<(QKV_OUT * HID / 16 + 255) / 256, 256, 0, stream>>>(w_qkv_q, wqkv_i8, QKV_OUT * HID / 16);
    conv_i2c<<<(HID * HID / 16 + 255) / 256, 256, 0, stream>>>(w_o_q, wo_i8, HID * HID / 16);
    gemm_i8<true><<<dim3(QKV_OUT / 128, T / 128), 256, 0, stream>>>(
        a_i8, wqkv_i8, act_scale, a_sum, w_qkv_scale, w_qkv_zero, qkv, T, QKV_OUT, HID);
  } else {
    gemm_i8<false><<<dim3(QKV_OUT / 128, T / 128), 256, 0, stream>>>(
        a_i8, w_qkv_q, act_scale, a_sum, w_qkv_scale, w_qkv_zero, qkv, T, QKV_OUT, HID);
  }
  split_kv<<<dim3(T / 64, NKV + NH), 256, 0, stream>>>(qkv, positions, Kh, Kl, Vth);
  attn_kernel<<<dim3(64, NKV), 256, 0, stream>>>(qkv, Kh, Kl, Vth, out);
  quant_kernel<<<T, 256, 0, stream>>>(out, q2, s2, sum2);
  if (wconv) {
    gemm_i8<true><<<dim3(HID / 128, T / 128), 256, 0, stream>>>(
        q2, wo_i8, s2, sum2, w_o_scale, w_o_zero, out, T, HID, HID);
  } else {
    gemm_i8<false><<<dim3(HID / 128, T / 128), 256, 0, stream>>>(
        q2, w_o_q, s2, sum2, w_o_scale, w_o_zero, out, T, HID, HID);
  }
}

// Round 11
// 538.046 us; speedup vs baseline: 1.4557x; 1.0160x over previous
//
#include <hip/hip_runtime.h>

#define T 2048
#define HID 4096
#define NH 32
#define NKV 8
#define HD 128
#define QKV_OUT ((NH + 2*NKV) * HD)   // 6144
#define SCALING 0.08838834764831843f  // 128^-0.5
#define ROPE_C 0.20762050593046014f   // log2(10000)/64

typedef __attribute__((ext_vector_type(8))) short bfrag;   // 8 bf16
typedef __attribute__((ext_vector_type(4))) float ffrag;   // 4 f32 acc
typedef __attribute__((ext_vector_type(4))) int  ifrag;    // 16 i8 / 4 i32 acc
typedef __attribute__((ext_vector_type(16))) char c16;

__device__ __forceinline__ short f2bf(float f) {
  unsigned u = __builtin_bit_cast(unsigned, f);
  u += 0x7fffu + ((u >> 16) & 1u);   // RNE
  return (short)(u >> 16);
}

// bf16x2 split: x ~= hi + lo, residual ~2^-17 * |x|
__device__ __forceinline__ void split2(float x, short& hi, short& lo) {
  unsigned u = __builtin_bit_cast(unsigned, x);
  unsigned uh = u + (0x7fffu + ((u >> 16) & 1u));
  hi = (short)(uh >> 16);
  float fh = __builtin_bit_cast(float, uh & 0xffff0000u);
  float r = x - fh;
  unsigned ur = __builtin_bit_cast(unsigned, r);
  ur += 0x7fffu + ((ur >> 16) & 1u);
  lo = (short)(ur >> 16);
}

// async global->LDS, 16 B per lane
__device__ __forceinline__ void gload_lds16(const void* g, void* l) {
  __builtin_amdgcn_global_load_lds(
      (const __attribute__((address_space(1))) unsigned int*)g,
      (__attribute__((address_space(3))) unsigned int*)l, 16, 0, 0);
}

// ---------------- fused a_sum + int8 pack of activations ----------------
__global__ __launch_bounds__(256)
void asum_conv(const int* __restrict__ qact, float* __restrict__ a_sum,
               char* __restrict__ a_i8) {
  __shared__ int red[256];
  const int t = blockIdx.x, tid = threadIdx.x;
  const int* row = qact + (size_t)t * HID + tid * 16;
  int s = 0;
  c16 o;
#pragma unroll
  for (int i = 0; i < 4; i++) {
    int4 v = *(const int4*)(row + i * 4);
    s += v.x + v.y + v.z + v.w;
    o[i*4+0] = (char)v.x; o[i*4+1] = (char)v.y;
    o[i*4+2] = (char)v.z; o[i*4+3] = (char)v.w;
  }
  *(c16*)(a_i8 + (size_t)t * HID + tid * 16) = o;
  red[tid] = s; __syncthreads();
  for (int off = 128; off > 0; off >>= 1) {
    if (tid < off) red[tid] += red[tid + off];
    __syncthreads();
  }
  if (tid == 0) a_sum[t] = (float)red[0];
}

// ---------------- int32 -> int8 pack (weights) ----------------
__global__ __launch_bounds__(256)
void conv_i2c(const int* __restrict__ src, char* __restrict__ dst, int n16) {
  int idx = blockIdx.x * 256 + threadIdx.x;
  if (idx >= n16) return;
  const int4* s4 = (const int4*)src + (size_t)idx * 4;
  c16 o;
#pragma unroll
  for (int j = 0; j < 4; j++) {
    int4 v = s4[j];
    o[j*4+0] = (char)v.x; o[j*4+1] = (char)v.y;
    o[j*4+2] = (char)v.z; o[j*4+3] = (char)v.w;
  }
  *(c16*)(dst + (size_t)idx * 16) = o;
}

// ---------------- W4A8 GEMM, exact i8 MFMA (pre-packed weights only) ------
__global__ __launch_bounds__(256)
void gemm_i8(const char* __restrict__ A, const char* __restrict__ W,
             const float* __restrict__ s_a, const float* __restrict__ asum,
             const float* __restrict__ s_w, const float* __restrict__ z_w,
             float* __restrict__ C, int M, int N, int K) {
  __shared__ __align__(16) char As[128 * 64];
  __shared__ __align__(16) char Bs[128 * 64];
  const int tid = threadIdx.x;
  const int lane = tid & 63;
  const int quad = lane >> 4, l15 = lane & 15;
  const int wave = tid >> 6;
  const int wm = (wave >> 1) * 64, wn = (wave & 1) * 64;
  const int bm = blockIdx.y * 128, bn = blockIdx.x * 128;
  const int sr = tid >> 2, sc = (tid & 3) * 16;

  ifrag acc[4][4];
#pragma unroll
  for (int mi = 0; mi < 4; mi++)
#pragma unroll
    for (int ni = 0; ni < 4; ni++)
      acc[mi][ni] = (ifrag){0, 0, 0, 0};

  for (int k0 = 0; k0 < K; k0 += 64) {
#pragma unroll
    for (int it = 0; it < 2; it++) {
      gload_lds16(A + (size_t)(bm + it * 64 + sr) * K + k0 + sc,
                  &As[it * 4096 + wave * 1024]);
      gload_lds16(W + (size_t)(bn + it * 64 + sr) * K + k0 + sc,
                  &Bs[it * 4096 + wave * 1024]);
    }
    __syncthreads();

    ifrag af[4], bfv[4];
#pragma unroll
    for (int mi = 0; mi < 4; mi++)
      af[mi] = *(const ifrag*)&As[(wm + mi * 16 + l15) * 64 + quad * 16];
#pragma unroll
    for (int ni = 0; ni < 4; ni++)
      bfv[ni] = *(const ifrag*)&Bs[(wn + ni * 16 + l15) * 64 + quad * 16];
#pragma unroll
    for (int mi = 0; mi < 4; mi++)
#pragma unroll
      for (int ni = 0; ni < 4; ni++)
        acc[mi][ni] = __builtin_amdgcn_mfma_i32_16x16x64_i8(
            af[mi], bfv[ni], acc[mi][ni], 0, 0, 0);
    __syncthreads();
  }

#pragma unroll
  for (int mi = 0; mi < 4; mi++) {
    int row0 = bm + wm + mi * 16 + quad * 4;
#pragma unroll
    for (int r = 0; r < 4; r++) {
      int row = row0 + r;
      float sa = s_a[row], av = asum[row];
#pragma unroll
      for (int ni = 0; ni < 4; ni++) {
        int col = bn + wn + ni * 16 + l15;
        C[(size_t)row * N + col] = (sa * s_w[col]) * ((float)acc[mi][ni][r] - z_w[col] * av);
      }
    }
  }
}

// ---- split/rope: y<NKV: K rope->hi/lo + V->bf16 transposed; else Q rope in-place
__global__ __launch_bounds__(256)
void split_kv(float* __restrict__ qkv, const int* __restrict__ positions,
              short* __restrict__ Kh, short* __restrict__ Kl,
              short* __restrict__ Vth) {
  __shared__ __align__(16) short Vh_lds[128 * 72];
  const int y = blockIdx.y;
  const int t0 = blockIdx.x * 64;
  const int tid = threadIdx.x;

  if (y >= NKV) {                      // ---- Q: rope in place ----
    const int h = y - NKV;
#pragma unroll
    for (int it = 0; it < 4; it++) {
      int c = tid + 256 * it;
      int key = c >> 4, dc = c & 15;
      float* qr = qkv + (size_t)(t0 + key) * QKV_OUT + (size_t)h * HD;
      float4 a = *(const float4*)(qr + dc * 4);
      float4 b = *(const float4*)(qr + dc * 4 + 64);
      float av[4] = {a.x, a.y, a.z, a.w};
      float bv[4] = {b.x, b.y, b.z, b.w};
      float pos = (float)positions[t0 + key];
#pragma unroll
      for (int jj = 0; jj < 4; jj++) {
        float fr = pos * exp2f(-ROPE_C * (float)(dc * 4 + jj));
        float sn, cs; sincosf(fr, &sn, &cs);
        float x1 = av[jj], x2 = bv[jj];
        av[jj] = x1 * cs - x2 * sn;
        bv[jj] = x2 * cs + x1 * sn;
      }
      *(float4*)(qr + dc * 4)      = make_float4(av[0], av[1], av[2], av[3]);
      *(float4*)(qr + dc * 4 + 64) = make_float4(bv[0], bv[1], bv[2], bv[3]);
    }
    return;
  }

  const int kvh = y;
  // K: rope + hi/lo split
#pragma unroll
  for (int it = 0; it < 4; it++) {
    int c = tid + 256 * it;
    int key = c >> 4, dc = c & 15;
    const float* kr = qkv + (size_t)(t0 + key) * QKV_OUT
                      + (size_t)NH * HD + (size_t)kvh * HD;
    float4 a = *(const float4*)(kr + dc * 4);
    float4 b = *(const float4*)(kr + dc * 4 + 64);
    float av[4] = {a.x, a.y, a.z, a.w};
    float bv[4] = {b.x, b.y, b.z, b.w};
    float pos = (float)positions[t0 + key];
    short4 ha, la, hb, lb;
    short hh, ll;
#pragma unroll
    for (int jj = 0; jj < 4; jj++) {
      float fr = pos * exp2f(-ROPE_C * (float)(dc * 4 + jj));
      float sn, cs; sincosf(fr, &sn, &cs);
      float x1 = av[jj], x2 = bv[jj];
      float r1 = x1 * cs - x2 * sn;
      float r2 = x2 * cs + x1 * sn;
      split2(r1, hh, ll); ((short*)&ha)[jj] = hh; ((short*)&la)[jj] = ll;
      split2(r2, hh, ll); ((short*)&hb)[jj] = hh; ((short*)&lb)[jj] = ll;
    }
    size_t o1 = (size_t)kvh * T * HD + (size_t)(t0 + key) * HD + dc * 4;
    *(short4*)(Kh + o1) = ha;      *(short4*)(Kl + o1) = la;
    *(short4*)(Kh + o1 + 64) = hb; *(short4*)(Kl + o1 + 64) = lb;
  }
  // V -> bf16 transposed
#pragma unroll
  for (int i = 0; i < 8; i++) {
    int c = tid + 256 * i;
    int key = c >> 5, dc = c & 31;
    float4 f = *(const float4*)(qkv + (size_t)(t0 + key) * QKV_OUT
                                + (size_t)(NH + NKV) * HD + (size_t)kvh * HD + dc * 4);
    Vh_lds[(dc*4+0)*72 + key] = f2bf(f.x);
    Vh_lds[(dc*4+1)*72 + key] = f2bf(f.y);
    Vh_lds[(dc*4+2)*72 + key] = f2bf(f.z);
    Vh_lds[(dc*4+3)*72 + key] = f2bf(f.w);
  }
  __syncthreads();
#pragma unroll
  for (int i = 0; i < 2; i++) {
    int c = tid + 256 * i;
    int row = c >> 2, cc = c & 3;
    size_t o = (size_t)kvh * HD * T + (size_t)row * T + t0 + cc * 8;
    *(bfrag*)(Vth + o) = *(const bfrag*)&Vh_lds[row * 72 + cc * 8];
  }
#pragma unroll
  for (int i = 0; i < 2; i++) {
    int c = tid + 256 * i;
    int row = c >> 2, cc = c & 3;
    size_t o = (size_t)kvh * HD * T + (size_t)row * T + t0 + 32 + cc * 8;
    *(bfrag*)(Vth + o) = *(const bfrag*)&Vh_lds[row * 72 + 32 + cc * 8];
  }
}

// ---------------- MFMA flash attention, balanced pairs + reg prefetch ------
// (R7/R10 structure: best measured.) Block: (kvh, pair). Two passes: qtile
// 127-pair (heavy) then pair (light); 65 ktiles/block, uniform. Wave wv =
// q-head kvh*4+wv, 16 rows. K hi/lo exact, V bf16, P bf16, l via ones-MFMA.
__global__ __launch_bounds__(256)
void attn_kernel(const float* __restrict__ qkv,
                 const short* __restrict__ Kh, const short* __restrict__ Kl,
                 const short* __restrict__ Vth,
                 float* __restrict__ attn) {
  __shared__ __align__(16) short Ksh[32 * 136];   // +4 banks/row: 2-way, free
  __shared__ __align__(16) short Ksl[32 * 136];
  __shared__ __align__(16) short Vsh[128 * 40];   // +20 banks/row: 2-way, free
  __shared__ __align__(16) short Psh[4 * 16 * 40];

  const int kvh = blockIdx.y;
  const int pair = blockIdx.x;                 // 0..63
  const int tid = threadIdx.x;
  const int lane = tid & 63;
  const int wv = tid >> 6;
  const int l15 = lane & 15, quad = lane >> 4;
  const int h = kvh * 4 + wv;
  short* Pw = Psh + wv * 16 * 40;

  const short* KhB = Kh + (size_t)kvh * T * HD;
  const short* KlB = Kl + (size_t)kvh * T * HD;
  const short* VhB = Vth + (size_t)kvh * HD * T;

  const int kr = tid >> 4, kc8 = (tid & 15) * 8;   // K staging: rows kr, kr+16
  const int vd = tid >> 2, vc8 = (tid & 3) * 8;    // V staging: dims vd, vd+64

  bfrag rkh0, rkh1, rkl0, rkl1, rv0, rv1;
  auto preload = [&](int k0) {
    rkh0 = *(const bfrag*)(KhB + (size_t)(k0 + kr) * HD + kc8);
    rkh1 = *(const bfrag*)(KhB + (size_t)(k0 + kr + 16) * HD + kc8);
    rkl0 = *(const bfrag*)(KlB + (size_t)(k0 + kr) * HD + kc8);
    rkl1 = *(const bfrag*)(KlB + (size_t)(k0 + kr + 16) * HD + kc8);
    rv0  = *(const bfrag*)(VhB + (size_t)vd * T + k0 + vc8);
    rv1  = *(const bfrag*)(VhB + (size_t)(vd + 64) * T + k0 + vc8);
  };
  preload(0);

  bfrag ones;
#pragma unroll
  for (int j = 0; j < 8; j++) ones[j] = (short)0x3f80;

  for (int pass = 0; pass < 2; pass++) {
    const int qt = pass ? pair : 127 - pair;
    const int q0 = qt * 16;
    const int nk = (q0 >> 5) + 1;              // keys 0..q0+15

    // Q fragments (already roped fp32), bf16x2 split
    bfrag qh[4], ql[4];
    const float* qrow = qkv + (size_t)(q0 + l15) * QKV_OUT + (size_t)h * HD;
#pragma unroll
    for (int kc = 0; kc < 4; kc++) {
      float4 f0 = *(const float4*)(qrow + kc * 32 + quad * 8);
      float4 f1 = *(const float4*)(qrow + kc * 32 + quad * 8 + 4);
      float fv[8] = {f0.x, f0.y, f0.z, f0.w, f1.x, f1.y, f1.z, f1.w};
#pragma unroll
      for (int j = 0; j < 8; j++) {
        short hi, lo; split2(fv[j], hi, lo);
        qh[kc][j] = hi; ql[kc][j] = lo;
      }
    }

    ffrag o[8], ol;
    ol = (ffrag){0.f, 0.f, 0.f, 0.f};
#pragma unroll
    for (int n = 0; n < 8; n++) o[n] = (ffrag){0.f, 0.f, 0.f, 0.f};
    float m_i[4] = {-1e30f, -1e30f, -1e30f, -1e30f};

    for (int kt = 0; kt < nk; kt++) {
      const int k0 = kt << 5;
      __syncthreads();                         // prev LDS consumed
      *(bfrag*)&Ksh[kr * 136 + kc8] = rkh0;
      *(bfrag*)&Ksh[(kr + 16) * 136 + kc8] = rkh1;
      *(bfrag*)&Ksl[kr * 136 + kc8] = rkl0;
      *(bfrag*)&Ksl[(kr + 16) * 136 + kc8] = rkl1;
      *(bfrag*)&Vsh[vd * 40 + vc8] = rv0;
      *(bfrag*)&Vsh[(vd + 64) * 40 + vc8] = rv1;
      if (kt + 1 < nk) preload(k0 + 32);       // hidden behind compute
      else if (pass == 0) preload(0);          // prime next pass
      __syncthreads();

      // ---- S = Q K^T (exact via hi/lo split) ----
      ffrag s[2];
      s[0] = (ffrag){0.f,0.f,0.f,0.f}; s[1] = (ffrag){0.f,0.f,0.f,0.f};
#pragma unroll
      for (int n = 0; n < 2; n++) {
#pragma unroll
        for (int kc = 0; kc < 4; kc++) {
          bfrag bh = *(const bfrag*)&Ksh[(n*16 + l15) * 136 + kc*32 + quad*8];
          bfrag bl = *(const bfrag*)&Ksl[(n*16 + l15) * 136 + kc*32 + quad*8];
          s[n] = __builtin_amdgcn_mfma_f32_16x16x32_bf16(qh[kc], bh, s[n], 0,0,0);
          s[n] = __builtin_amdgcn_mfma_f32_16x16x32_bf16(qh[kc], bl, s[n], 0,0,0);
          s[n] = __builtin_amdgcn_mfma_f32_16x16x32_bf16(ql[kc], bh, s[n], 0,0,0);
        }
      }
      // ---- online softmax ----
      const bool last = (kt == nk - 1);
      float sv[2][4];
#pragma unroll
      for (int n = 0; n < 2; n++)
#pragma unroll
        for (int r = 0; r < 4; r++) {
          float v = s[n][r] * SCALING;
          if (last) {
            int key = k0 + n * 16 + l15;
            int row = q0 + quad * 4 + r;
            if (key > row) v = -1e30f;
          }
          sv[n][r] = v;
        }
      float alpha[4];
      bool anyup = false;
#pragma unroll
      for (int r = 0; r < 4; r++) {
        float mt = fmaxf(sv[0][r], sv[1][r]);
        mt = fmaxf(mt, __shfl_xor(mt, 1));
        mt = fmaxf(mt, __shfl_xor(mt, 2));
        mt = fmaxf(mt, __shfl_xor(mt, 4));
        mt = fmaxf(mt, __shfl_xor(mt, 8));
        float m_new = fmaxf(m_i[r], mt);
        alpha[r] = __expf(m_i[r] - m_new);
        if (m_new > m_i[r]) anyup = true;
        m_i[r] = m_new;
      }
#pragma unroll
      for (int n = 0; n < 2; n++)
#pragma unroll
        for (int r = 0; r < 4; r++) {
          float p = __expf(sv[n][r] - m_i[r]);
          Pw[(quad*4 + r) * 40 + n*16 + l15] = f2bf(p);
        }
      if (__any(anyup)) {                      // wave-uniform rescale skip
#pragma unroll
        for (int r = 0; r < 4; r++) ol[r] *= alpha[r];
#pragma unroll
        for (int n = 0; n < 8; n++)
#pragma unroll
          for (int r = 0; r < 4; r++) o[n][r] *= alpha[r];
      }
      // ---- PV; l via ones-MFMA (same wave wrote Pw, no barrier) ----
      bfrag ph = *(const bfrag*)&Pw[l15 * 40 + quad * 8];
      ol = __builtin_amdgcn_mfma_f32_16x16x32_bf16(ph, ones, ol, 0,0,0);
#pragma unroll
      for (int n = 0; n < 8; n++) {
        bfrag vh = *(const bfrag*)&Vsh[(n*16 + l15) * 40 + quad * 8];
        o[n] = __builtin_amdgcn_mfma_f32_16x16x32_bf16(ph, vh, o[n], 0,0,0);
      }
    }

    float inv[4];
#pragma unroll
    for (int r = 0; r < 4; r++) inv[r] = 1.f / ol[r];
#pragma unroll
    for (int n = 0; n < 8; n++)
#pragma unroll
      for (int r = 0; r < 4; r++) {
        int row = q0 + quad * 4 + r;
        attn[(size_t)row * HID + (size_t)h * HD + n * 16 + l15] = o[n][r] * inv[r];
      }
  }
}

// ---------------- dynamic quant with sum (i8 out) ----------------
__global__ __launch_bounds__(256)
void quant_kernel(const float* __restrict__ x, char* __restrict__ q2,
                  float* __restrict__ s2, float* __restrict__ sum2) {
  __shared__ float red[256];
  const int t = blockIdx.x, tid = threadIdx.x;
  const float* row = x + (size_t)t * HID;
  float4 v[4];
  float m = 0.f;
#pragma unroll
  for (int i = 0; i < 4; i++) {
    v[i] = *(const float4*)(row + tid * 16 + i * 4);
    m = fmaxf(m, fmaxf(fmaxf(fabsf(v[i].x), fabsf(v[i].y)),
                       fmaxf(fabsf(v[i].z), fabsf(v[i].w))));
  }
  red[tid] = m; __syncthreads();
  for (int off = 128; off > 0; off >>= 1) {
    if (tid < off) red[tid] = fmaxf(red[tid], red[tid + off]);
    __syncthreads();
  }
  float s = fmaxf(red[0], 1e-8f) / 127.f;
  __syncthreads();
  float ssum = 0.f;
  c16 o;
#pragma unroll
  for (int i = 0; i < 4; i++) {
    float q;
    q = fminf(127.f, fmaxf(-127.f, rintf(v[i].x / s))); ssum += q; o[i*4+0] = (char)(int)q;
    q = fminf(127.f, fmaxf(-127.f, rintf(v[i].y / s))); ssum += q; o[i*4+1] = (char)(int)q;
    q = fminf(127.f, fmaxf(-127.f, rintf(v[i].z / s))); ssum += q; o[i*4+2] = (char)(int)q;
    q = fminf(127.f, fmaxf(-127.f, rintf(v[i].w / s))); ssum += q; o[i*4+3] = (char)(int)q;
  }
  *(c16*)(q2 + (size_t)t * HID + tid * 16) = o;
  red[tid] = ssum; __syncthreads();
  for (int off = 128; off > 0; off >>= 1) {
    if (tid < off) red[tid] += red[tid + off];
    __syncthreads();
  }
  if (tid == 0) { s2[t] = s; sum2[t] = red[0]; }
}

// ---------------- launch ----------------
// Workspace layout (~109 MB, <= 117.5 MB proven by R5's passing run):
//   act8: shared by a_i8 (dead after QKV GEMM) and q2 (written by quant later)
//   w8:   shared by wqkv_i8 (dead after QKV GEMM) and wo_i8 (packed after attn)
extern "C" void kernel_launch(void* const* d_in, const int* in_sizes, int n_in,
                              void* d_out, int out_size, void* d_ws, size_t ws_size,
                              hipStream_t stream) {
  const int*   positions   = (const int*)d_in[0];
  const int*   q_act       = (const int*)d_in[1];
  const float* act_scale   = (const float*)d_in[2];
  const int*   w_qkv_q     = (const int*)d_in[3];
  const float* w_qkv_scale = (const float*)d_in[4];
  const float* w_qkv_zero  = (const float*)d_in[5];
  const int*   w_o_q       = (const int*)d_in[6];
  const float* w_o_scale   = (const float*)d_in[7];
  const float* w_o_zero    = (const float*)d_in[8];
  float* out = (float*)d_out;

  size_t off = 0;
  auto alloc = [&](size_t bytes) -> void* {
    void* p = (char*)d_ws + off;
    off += (bytes + 255) & ~(size_t)255;
    return p;
  };
  float* qkv   = (float*)alloc((size_t)T * QKV_OUT * 4);         // 50.3 MB
  char*  act8  = (char*)alloc((size_t)T * HID);                  //  8.4 MB (a_i8 / q2)
  short* Kh    = (short*)alloc((size_t)NKV * T * HD * 2);        //  8.4 MB
  short* Kl    = (short*)alloc((size_t)NKV * T * HD * 2);        //  8.4 MB
  short* Vth   = (short*)alloc((size_t)NKV * T * HD * 2);        //  8.4 MB
  char*  w8    = (char*)alloc((size_t)QKV_OUT * HID);            // 25.2 MB (wqkv / wo)
  float* a_sum = (float*)alloc(T * 4);
  float* s2    = (float*)alloc(T * 4);
  float* sum2  = (float*)alloc(T * 4);
  (void)ws_size;

  asum_conv<<<T, 256, 0, stream>>>(q_act, a_sum, act8);
  conv_i2c<<<(QKV_OUT * HID / 16 + 255) / 256, 256, 0, stream>>>(
      w_qkv_q, w8, QKV_OUT * HID / 16);
  gemm_i8<<<dim3(QKV_OUT / 128, T / 128), 256, 0, stream>>>(
      act8, w8, act_scale, a_sum, w_qkv_scale, w_qkv_zero, qkv, T, QKV_OUT, HID);
  split_kv<<<dim3(T / 64, NKV + NH), 256, 0, stream>>>(qkv, positions, Kh, Kl, Vth);
  attn_kernel<<<dim3(64, NKV), 256, 0, stream>>>(qkv, Kh, Kl, Vth, out);
  conv_i2c<<<(HID * HID / 16 + 255) / 256, 256, 0, stream>>>(
      w_o_q, w8, HID * HID / 16);                 // wqkv dead; reuse w8
  quant_kernel<<<T, 256, 0, stream>>>(out, act8, s2, sum2);   // a_i8 dead; reuse act8
  gemm_i8<<<dim3(HID / 128, T / 128), 256, 0, stream>>>(
      act8, w8, s2, sum2, w_o_scale, w_o_zero, out, T, HID, HID);
}